// Round 1
// baseline (2044.168 us; speedup 1.0000x reference)
//
#include <hip/hip_runtime.h>
#include <stdint.h>

// Problem constants (match reference)
#define USER_N 100000
#define ITEM_N 50000
#define TAG_N  20000
#define NN (USER_N + ITEM_N)   // 150000 interaction-graph nodes
#define MM (ITEM_N + TAG_N)    // 70000 tag-graph nodes
#define DD 64

// ---------------------------------------------------------------------------
// JAX threefry2x32 (20 rounds), bit-exact. key=(k0,k1), counter=(x0,x1).
// ---------------------------------------------------------------------------
__host__ __device__ __forceinline__ void tf2x32(uint32_t k0, uint32_t k1,
                                                uint32_t x0, uint32_t x1,
                                                uint32_t* o0, uint32_t* o1) {
  uint32_t ks2 = k0 ^ k1 ^ 0x1BD11BDAu;
#define ROTL32(v, d) (((v) << (d)) | ((v) >> (32 - (d))))
#define TF_RND(d) { x0 += x1; x1 = ROTL32(x1, d); x1 ^= x0; }
  x0 += k0; x1 += k1;
  TF_RND(13) TF_RND(15) TF_RND(26) TF_RND(6)
  x0 += k1;  x1 += ks2 + 1u;
  TF_RND(17) TF_RND(29) TF_RND(16) TF_RND(24)
  x0 += ks2; x1 += k0 + 2u;
  TF_RND(13) TF_RND(15) TF_RND(26) TF_RND(6)
  x0 += k0;  x1 += k1 + 3u;
  TF_RND(17) TF_RND(29) TF_RND(16) TF_RND(24)
  x0 += k1;  x1 += ks2 + 4u;
  TF_RND(13) TF_RND(15) TF_RND(26) TF_RND(6)
  x0 += ks2; x1 += k0 + 5u;
  *o0 = x0; *o1 = x1;
#undef TF_RND
#undef ROTL32
}

// ---------------------------------------------------------------------------
// drop-edge: dval[e] = vals[e] * floor(u+0.9) * (1/0.9), u = jax uniform
// (partitionable threefry: bits(e) = o0 ^ o1 of hash of 64-bit index e)
// ---------------------------------------------------------------------------
__global__ void drop_kernel(const float* __restrict__ vals,
                            float* __restrict__ dval, int n,
                            uint32_t k0, uint32_t k1) {
  int e = blockIdx.x * blockDim.x + threadIdx.x;
  if (e >= n) return;
  uint32_t o0, o1;
  tf2x32(k0, k1, 0u, (uint32_t)e, &o0, &o1);
  uint32_t bits = o0 ^ o1;
  float u = __uint_as_float((bits >> 9) | 0x3F800000u) - 1.0f;
  float m = floorf(u + 0.9f);               // 1.0 keep, 0.0 drop (bit-exact f32)
  const float SC = (float)(1.0 / 0.9);      // f32 of python 1.0/KEEP
  dval[e] = vals[e] * m * SC;
}

// ---------------------------------------------------------------------------
// SpMM scatter: one wave (64 lanes) per edge; lane = feature dim.
// Gather source is a virtual concat: col < split -> srcA[col], else srcB[col-split]
// ---------------------------------------------------------------------------
__global__ void spmm_kernel(const int* __restrict__ rows, const int* __restrict__ cols,
                            const float* __restrict__ vals,
                            const float* __restrict__ srcA, const float* __restrict__ srcB,
                            int split, float* __restrict__ out, int nE) {
  int e = (blockIdx.x * blockDim.x + threadIdx.x) >> 6;
  if (e >= nE) return;
  int lane = threadIdx.x & 63;
  float v = vals[e];
  if (v == 0.0f) return;                    // dropped edge: adds exact zero
  int r = rows[e];
  int c = cols[e];
  const float* src = (c < split) ? (srcA + (size_t)c * DD)
                                 : (srcB + (size_t)(c - split) * DD);
  atomicAdd(out + (size_t)r * DD + lane, v * src[lane]);
}

__device__ __forceinline__ float4 lk4(float4 x) {
  x.x = x.x >= 0.0f ? x.x : 0.5f * x.x;
  x.y = x.y >= 0.0f ? x.y : 0.5f * x.y;
  x.z = x.z >= 0.0f ? x.z : 0.5f * x.z;
  x.w = x.w >= 0.0f ? x.w : 0.5f * x.w;
  return x;
}

// acc = lat0 = concat(uEmbeds, iEmbeds); d_out doubles as layer-0 lat.
__global__ void init_kernel(const float4* __restrict__ u, const float4* __restrict__ it,
                            float4* __restrict__ acc) {
  int idx = blockIdx.x * blockDim.x + threadIdx.x;   // over NN*16 float4s
  if (idx >= NN * 16) return;
  const int uN = USER_N * 16;
  acc[idx] = (idx < uN) ? u[idx] : it[idx - uN];
}

__global__ void leaky_kernel(float4* __restrict__ x, int n) {
  int idx = blockIdx.x * blockDim.x + threadIdx.x;
  if (idx < n) x[idx] = lk4(x[idx]);
}

// lat_new = concat(leaky(h)[:USER] + leaky(s), leaky(h)[USER:] + tg[:ITEM])
// acc += lat_new; optionally store lat_new. tg is ALREADY activated.
template <bool STORE>
__global__ void combine_kernel(const float4* __restrict__ hbuf,
                               const float4* __restrict__ sbuf,
                               const float4* __restrict__ tg,
                               float4* __restrict__ latOut,
                               float4* __restrict__ acc) {
  int idx = blockIdx.x * blockDim.x + threadIdx.x;   // over NN*16
  if (idx >= NN * 16) return;
  int r = idx >> 4;
  float4 t = lk4(hbuf[idx]);
  float4 o;
  if (r < USER_N) {
    float4 s = lk4(sbuf[idx]);
    o = make_float4(t.x + s.x, t.y + s.y, t.z + s.z, t.w + s.w);
  } else {
    float4 g = tg[idx - USER_N * 16];
    o = make_float4(t.x + g.x, t.y + g.y, t.z + g.z, t.w + g.w);
  }
  float4 a = acc[idx];
  a.x += o.x; a.y += o.y; a.z += o.z; a.w += o.w;
  acc[idx] = a;
  if (STORE) latOut[idx] = o;
}

extern "C" void kernel_launch(void* const* d_in, const int* in_sizes, int n_in,
                              void* d_out, int out_size, void* d_ws, size_t ws_size,
                              hipStream_t stream) {
  const float* uE    = (const float*)d_in[0];
  const float* iE    = (const float*)d_in[1];
  const float* tEm   = (const float*)d_in[2];
  const int*   adj_r = (const int*)d_in[3];
  const int*   adj_c = (const int*)d_in[4];
  const float* adj_v = (const float*)d_in[5];
  const int*   tag_r = (const int*)d_in[6];
  const int*   tag_c = (const int*)d_in[7];
  const float* tag_v = (const float*)d_in[8];
  const int*   soc_r = (const int*)d_in[9];
  const int*   soc_c = (const int*)d_in[10];
  const float* soc_v = (const float*)d_in[11];
  const int nAdj = in_sizes[5], nTag = in_sizes[8], nSoc = in_sizes[11];

  float* acc = (float*)d_out;
  // Workspace layout (~146 MB of f32):
  float* lat1 = (float*)d_ws;                 // NN*DD      : layer-0 output lat
  float* hbuf = lat1 + (size_t)NN * DD;       // NN*DD      : adj spmm accum
  float* sbuf = hbuf + (size_t)NN * DD;       // USER_N*DD  : soc spmm accum
  float* tg1  = sbuf + (size_t)USER_N * DD;   // MM*DD      : tag_lat layer 1
  float* tg2  = tg1  + (size_t)MM * DD;       // MM*DD      : layer-1 tag output
  float* dval = tg2  + (size_t)MM * DD;       // nAdj       : dropped edge vals

  // fold_in(key(42), j) for j=0..5 (host-side, deterministic)
  uint32_t kk[6][2];
  for (uint32_t j = 0; j < 6; ++j) tf2x32(0u, 42u, 0u, j, &kk[j][0], &kk[j][1]);

  const int thr = 256;
  // acc = lat0
  init_kernel<<<(NN * 16 + thr - 1) / thr, thr, 0, stream>>>(
      (const float4*)uE, (const float4*)iE, (float4*)acc);

  for (int layer = 0; layer < 2; ++layer) {
    const float* lat   = (layer == 0) ? acc : lat1;
    float*       tgOut = (layer == 0) ? tg1 : tg2;
    hipMemsetAsync(hbuf, 0, (size_t)NN * DD * sizeof(float), stream);
    hipMemsetAsync(sbuf, 0, (size_t)USER_N * DD * sizeof(float), stream);
    hipMemsetAsync(tgOut, 0, (size_t)MM * DD * sizeof(float), stream);

    // tem = gcn(adj, drop(adj_v), lat, NN)
    drop_kernel<<<(nAdj + thr - 1) / thr, thr, 0, stream>>>(adj_v, dval, nAdj,
                                                            kk[3 * layer][0], kk[3 * layer][1]);
    spmm_kernel<<<(int)(((size_t)nAdj * 64 + thr - 1) / thr), thr, 0, stream>>>(
        adj_r, adj_c, dval, lat, lat, NN, hbuf, nAdj);

    // tg = gcn(tag, drop(tag_v), concat(lat[USER:], tag_lat[ITEM:]), MM)
    const float* tA = lat + (size_t)USER_N * DD;               // items part of lat
    const float* tB = (layer == 0) ? tEm : (tg1 + (size_t)ITEM_N * DD);  // tags part
    drop_kernel<<<(nTag + thr - 1) / thr, thr, 0, stream>>>(tag_v, dval, nTag,
                                                            kk[3 * layer + 1][0], kk[3 * layer + 1][1]);
    spmm_kernel<<<(int)(((size_t)nTag * 64 + thr - 1) / thr), thr, 0, stream>>>(
        tag_r, tag_c, dval, tA, tB, ITEM_N, tgOut, nTag);

    // soc = gcn(soc, drop(soc_v), lat[:USER], USER)
    drop_kernel<<<(nSoc + thr - 1) / thr, thr, 0, stream>>>(soc_v, dval, nSoc,
                                                            kk[3 * layer + 2][0], kk[3 * layer + 2][1]);
    spmm_kernel<<<(int)(((size_t)nSoc * 64 + thr - 1) / thr), thr, 0, stream>>>(
        soc_r, soc_c, dval, lat, lat, NN, sbuf, nSoc);

    // tg activation in place (tg becomes next tag_lat / combine input)
    leaky_kernel<<<(MM * 16 + thr - 1) / thr, thr, 0, stream>>>((float4*)tgOut, MM * 16);

    // lat_new + acc update
    if (layer == 0)
      combine_kernel<true><<<(NN * 16 + thr - 1) / thr, thr, 0, stream>>>(
          (const float4*)hbuf, (const float4*)sbuf, (const float4*)tgOut,
          (float4*)lat1, (float4*)acc);
    else
      combine_kernel<false><<<(NN * 16 + thr - 1) / thr, thr, 0, stream>>>(
          (const float4*)hbuf, (const float4*)sbuf, (const float4*)tgOut,
          nullptr, (float4*)acc);
  }
}

// Round 2
// 1197.747 us; speedup vs baseline: 1.7067x; 1.7067x over previous
//
#include <hip/hip_runtime.h>
#include <stdint.h>

// Problem constants (match reference)
#define USER_N 100000
#define ITEM_N 50000
#define TAG_N  20000
#define NN (USER_N + ITEM_N)   // 150000 interaction-graph nodes
#define MM (ITEM_N + TAG_N)    // 70000 tag-graph nodes
#define DD 64

// ---------------------------------------------------------------------------
// JAX threefry2x32 (20 rounds), bit-exact. key=(k0,k1), counter=(x0,x1).
// Verified bit-exact vs jax in R1 (absmax 0.0).
// ---------------------------------------------------------------------------
__host__ __device__ __forceinline__ void tf2x32(uint32_t k0, uint32_t k1,
                                                uint32_t x0, uint32_t x1,
                                                uint32_t* o0, uint32_t* o1) {
  uint32_t ks2 = k0 ^ k1 ^ 0x1BD11BDAu;
#define ROTL32(v, d) (((v) << (d)) | ((v) >> (32 - (d))))
#define TF_RND(d) { x0 += x1; x1 = ROTL32(x1, d); x1 ^= x0; }
  x0 += k0; x1 += k1;
  TF_RND(13) TF_RND(15) TF_RND(26) TF_RND(6)
  x0 += k1;  x1 += ks2 + 1u;
  TF_RND(17) TF_RND(29) TF_RND(16) TF_RND(24)
  x0 += ks2; x1 += k0 + 2u;
  TF_RND(13) TF_RND(15) TF_RND(26) TF_RND(6)
  x0 += k0;  x1 += k1 + 3u;
  TF_RND(17) TF_RND(29) TF_RND(16) TF_RND(24)
  x0 += k1;  x1 += ks2 + 4u;
  TF_RND(13) TF_RND(15) TF_RND(26) TF_RND(6)
  x0 += ks2; x1 += k0 + 5u;
  *o0 = x0; *o1 = x1;
#undef TF_RND
#undef ROTL32
}

// drop-edge: dval[e] = vals[e] * floor(u+0.9) * (1/0.9)
__global__ void drop_kernel(const float* __restrict__ vals,
                            float* __restrict__ dval, int n,
                            uint32_t k0, uint32_t k1) {
  int e = blockIdx.x * blockDim.x + threadIdx.x;
  if (e >= n) return;
  uint32_t o0, o1;
  tf2x32(k0, k1, 0u, (uint32_t)e, &o0, &o1);
  uint32_t bits = o0 ^ o1;
  float u = __uint_as_float((bits >> 9) | 0x3F800000u) - 1.0f;
  float m = floorf(u + 0.9f);
  const float SC = (float)(1.0 / 0.9);
  dval[e] = vals[e] * m * SC;
}

// ---------------------------------------------------------------------------
// CSR build: histogram -> hierarchical exclusive scan -> scatter (col, eid)
// ---------------------------------------------------------------------------
__global__ void hist_kernel(const int* __restrict__ rows, int* __restrict__ cnt, int nE) {
  int e = blockIdx.x * blockDim.x + threadIdx.x;
  if (e < nE) atomicAdd(&cnt[rows[e]], 1);
}

// block = 256 threads, 1024 elements/block. Exclusive scan within block.
__global__ void scan1_kernel(const int* __restrict__ cnt, int* __restrict__ rp,
                             int* __restrict__ bsum, int n) {
  __shared__ int s[256];
  int t = threadIdx.x;
  int base = blockIdx.x * 1024 + t * 4;
  int c0 = (base + 0 < n) ? cnt[base + 0] : 0;
  int c1 = (base + 1 < n) ? cnt[base + 1] : 0;
  int c2 = (base + 2 < n) ? cnt[base + 2] : 0;
  int c3 = (base + 3 < n) ? cnt[base + 3] : 0;
  int tsum = c0 + c1 + c2 + c3;
  s[t] = tsum;
  __syncthreads();
  for (int off = 1; off < 256; off <<= 1) {
    int v = (t >= off) ? s[t - off] : 0;
    __syncthreads();
    s[t] += v;
    __syncthreads();
  }
  int excl = s[t] - tsum;
  if (base + 0 < n) rp[base + 0] = excl;
  if (base + 1 < n) rp[base + 1] = excl + c0;
  if (base + 2 < n) rp[base + 2] = excl + c0 + c1;
  if (base + 3 < n) rp[base + 3] = excl + c0 + c1 + c2;
  if (t == 255) bsum[blockIdx.x] = s[255];
}

// single block, B <= 256 block sums -> exclusive scan in place
__global__ void scan2_kernel(int* __restrict__ bsum, int B) {
  __shared__ int s[256];
  int t = threadIdx.x;
  int v = (t < B) ? bsum[t] : 0;
  s[t] = v;
  __syncthreads();
  for (int off = 1; off < 256; off <<= 1) {
    int x = (t >= off) ? s[t - off] : 0;
    __syncthreads();
    s[t] += x;
    __syncthreads();
  }
  if (t < B) bsum[t] = s[t] - v;
}

__global__ void scan3_kernel(int* __restrict__ rp, const int* __restrict__ bsum,
                             int* __restrict__ cursor, int n, int nE) {
  int i = blockIdx.x * blockDim.x + threadIdx.x;
  if (i < n) {
    int v = rp[i] + bsum[i >> 10];
    rp[i] = v;
    cursor[i] = v;
  }
  if (i == 0) rp[n] = nE;
}

__global__ void scatter_kernel(const int* __restrict__ rows, const int* __restrict__ cols,
                               int* __restrict__ cursor,
                               int* __restrict__ col_s, int* __restrict__ eid_s, int nE) {
  int e = blockIdx.x * blockDim.x + threadIdx.x;
  if (e >= nE) return;
  int pos = atomicAdd(&cursor[rows[e]], 1);
  col_s[pos] = cols[e];
  eid_s[pos] = e;
}

// ---------------------------------------------------------------------------
// Gather SpMM core: one wave per row, lane = feature dim.
// Edge meta loaded coalesced in 64-chunks, broadcast via shfl.
// ---------------------------------------------------------------------------
__device__ __forceinline__ float gather_row(int s0, int s1,
                                            const int* __restrict__ col,
                                            const int* __restrict__ eid,
                                            const float* __restrict__ dv,
                                            const float* __restrict__ srcA,
                                            const float* __restrict__ srcB,
                                            int split, int lane) {
  float a = 0.0f;
  for (int base = s0; base < s1; base += 64) {
    int i = base + lane;
    int c = 0;
    float v = 0.0f;
    if (i < s1) {
      v = dv[eid[i]];
      c = col[i];
    }
    int cnt = s1 - base;
    if (cnt > 64) cnt = 64;
    for (int j = 0; j < cnt; ++j) {
      float vj = __shfl(v, j);
      if (vj != 0.0f) {
        int cj = __shfl(c, j);
        const float* s = (cj < split) ? (srcA + (size_t)cj * DD)
                                      : (srcB + (size_t)(cj - split) * DD);
        a += vj * s[lane];
      }
    }
  }
  return a;
}

__device__ __forceinline__ float lky(float x) { return x >= 0.0f ? x : 0.5f * x; }

// Standalone tag gather (layer 0 only): out = leaky(spmm), rows [0,MM)
__global__ void gather_tag_kernel(const int* __restrict__ rp, const int* __restrict__ col,
                                  const int* __restrict__ eid, const float* __restrict__ dv,
                                  const float* __restrict__ srcA, const float* __restrict__ srcB,
                                  float* __restrict__ out) {
  int r = (blockIdx.x * blockDim.x + threadIdx.x) >> 6;
  if (r >= MM) return;
  int lane = threadIdx.x & 63;
  float a = gather_row(rp[r], rp[r + 1], col, eid, dv, srcA, srcB, ITEM_N, lane);
  out[(size_t)r * DD + lane] = lky(a);
}

// Mega gather over NN rows: adj gather + fused soc (r<USER) + tg combine,
// epilogue: o = leaky(adj) + (leaky(soc) | tg_row); acc += o; [lat1 = o]
// FUSE_TAG (layer 1): tag gather computed inline for r>=USER instead of tgbuf.
template <bool STORE, bool FUSE_TAG>
__global__ void gather_mega_kernel(
    const int* __restrict__ arp, const int* __restrict__ acol,
    const int* __restrict__ aeid, const float* __restrict__ adv,
    const int* __restrict__ srp, const int* __restrict__ scol,
    const int* __restrict__ seid, const float* __restrict__ sdv,
    const int* __restrict__ trp, const int* __restrict__ tcol,
    const int* __restrict__ teid, const float* __restrict__ tdv,
    const float* __restrict__ lat,    // NN x 64, src for adj & soc (& tag A part)
    const float* __restrict__ tgbuf,  // !FUSE_TAG: pre-leaky'd tg rows
    const float* __restrict__ tagB,   // FUSE_TAG: tag-node src rows
    float* __restrict__ latOut, float* __restrict__ acc) {
  int r = (blockIdx.x * blockDim.x + threadIdx.x) >> 6;
  if (r >= NN) return;
  int lane = threadIdx.x & 63;
  float a = gather_row(arp[r], arp[r + 1], acol, aeid, adv, lat, lat, NN, lane);
  float t = lky(a);
  float o;
  if (r < USER_N) {
    float s = gather_row(srp[r], srp[r + 1], scol, seid, sdv, lat, lat, NN, lane);
    o = t + lky(s);
  } else {
    int tr = r - USER_N;
    if (FUSE_TAG) {
      float g = gather_row(trp[tr], trp[tr + 1], tcol, teid, tdv,
                           lat + (size_t)USER_N * DD, tagB, ITEM_N, lane);
      o = t + lky(g);
    } else {
      o = t + tgbuf[(size_t)tr * DD + lane];
    }
  }
  size_t idx = (size_t)r * DD + lane;
  acc[idx] += o;
  if (STORE) latOut[idx] = o;
}

// acc = lat0 = concat(uEmbeds, iEmbeds); also keep a separate lat0 copy in ws
// (gather epilogue RMWs acc while reading lat0 -> must not alias).
__global__ void init_kernel(const float4* __restrict__ u, const float4* __restrict__ it,
                            float4* __restrict__ lat0, float4* __restrict__ acc) {
  int idx = blockIdx.x * blockDim.x + threadIdx.x;  // over NN*16 float4s
  if (idx >= NN * 16) return;
  const int uN = USER_N * 16;
  float4 v = (idx < uN) ? u[idx] : it[idx - uN];
  lat0[idx] = v;
  acc[idx] = v;
}

extern "C" void kernel_launch(void* const* d_in, const int* in_sizes, int n_in,
                              void* d_out, int out_size, void* d_ws, size_t ws_size,
                              hipStream_t stream) {
  const float* uE    = (const float*)d_in[0];
  const float* iE    = (const float*)d_in[1];
  const float* tEm   = (const float*)d_in[2];
  const int*   adj_r = (const int*)d_in[3];
  const int*   adj_c = (const int*)d_in[4];
  const float* adj_v = (const float*)d_in[5];
  const int*   tag_r = (const int*)d_in[6];
  const int*   tag_c = (const int*)d_in[7];
  const float* tag_v = (const float*)d_in[8];
  const int*   soc_r = (const int*)d_in[9];
  const int*   soc_c = (const int*)d_in[10];
  const float* soc_v = (const float*)d_in[11];
  const int nAdj = in_sizes[5], nTag = in_sizes[8], nSoc = in_sizes[11];

  float* acc = (float*)d_out;

  // Workspace layout (~145.3 MB total; R1 used 146.5 MB successfully)
  float* lat0 = (float*)d_ws;                    // NN*DD
  float* lat1 = lat0 + (size_t)NN * DD;          // NN*DD
  float* tg1  = lat1 + (size_t)NN * DD;          // MM*DD
  float* adv  = tg1  + (size_t)MM * DD;          // nAdj
  float* tdv  = adv  + nAdj;                     // nTag
  float* sdv  = tdv  + nTag;                     // nSoc
  int* ip     = (int*)(sdv + nSoc);
  int* a_rp  = ip;            ip += NN + 1;
  int* a_cur = ip;            ip += NN;
  int* a_col = ip;            ip += nAdj;
  int* a_eid = ip;            ip += nAdj;
  int* t_rp  = ip;            ip += MM + 1;
  int* t_cur = ip;            ip += MM;
  int* t_col = ip;            ip += nTag;
  int* t_eid = ip;            ip += nTag;
  int* s_rp  = ip;            ip += USER_N + 1;
  int* s_cur = ip;            ip += USER_N;
  int* s_col = ip;            ip += nSoc;
  int* s_eid = ip;            ip += nSoc;
  int* bsum  = ip;            ip += 256;

  // fold_in(key(42), j) for j=0..5 (host-side, deterministic)
  uint32_t kk[6][2];
  for (uint32_t j = 0; j < 6; ++j) tf2x32(0u, 42u, 0u, j, &kk[j][0], &kk[j][1]);

  const int thr = 256;
#define CDIV(a, b) (((a) + (b) - 1) / (b))

  // ---- CSR build (once per call; reused across both layers) ----
  struct G { const int* rows; const int* cols; int n; int nE; int* rp; int* cur; int* col; int* eid; };
  G gs[3] = {
      {adj_r, adj_c, NN,     nAdj, a_rp, a_cur, a_col, a_eid},
      {tag_r, tag_c, MM,     nTag, t_rp, t_cur, t_col, t_eid},
      {soc_r, soc_c, USER_N, nSoc, s_rp, s_cur, s_col, s_eid},
  };
  for (int g = 0; g < 3; ++g) {
    hipMemsetAsync(gs[g].cur, 0, (size_t)gs[g].n * sizeof(int), stream);
    hist_kernel<<<CDIV(gs[g].nE, thr), thr, 0, stream>>>(gs[g].rows, gs[g].cur, gs[g].nE);
    int B = CDIV(gs[g].n, 1024);
    scan1_kernel<<<B, 256, 0, stream>>>(gs[g].cur, gs[g].rp, bsum, gs[g].n);
    scan2_kernel<<<1, 256, 0, stream>>>(bsum, B);
    scan3_kernel<<<CDIV(gs[g].n, thr), thr, 0, stream>>>(gs[g].rp, bsum, gs[g].cur, gs[g].n, gs[g].nE);
    scatter_kernel<<<CDIV(gs[g].nE, thr), thr, 0, stream>>>(gs[g].rows, gs[g].cols, gs[g].cur,
                                                            gs[g].col, gs[g].eid, gs[g].nE);
  }

  // ---- init: acc = lat0 = concat(u, i) ----
  init_kernel<<<CDIV(NN * 16, thr), thr, 0, stream>>>(
      (const float4*)uE, (const float4*)iE, (float4*)lat0, (float4*)acc);

  // ---- layer 0 ----
  drop_kernel<<<CDIV(nAdj, thr), thr, 0, stream>>>(adj_v, adv, nAdj, kk[0][0], kk[0][1]);
  drop_kernel<<<CDIV(nTag, thr), thr, 0, stream>>>(tag_v, tdv, nTag, kk[1][0], kk[1][1]);
  drop_kernel<<<CDIV(nSoc, thr), thr, 0, stream>>>(soc_v, sdv, nSoc, kk[2][0], kk[2][1]);

  // tg1 = leaky(tag-spmm) over all MM rows (needed as tag_lat next layer)
  gather_tag_kernel<<<CDIV(MM * 64, thr), thr, 0, stream>>>(
      t_rp, t_col, t_eid, tdv, lat0 + (size_t)USER_N * DD, tEm, tg1);

  // lat1 = combine(leaky(adj-spmm), leaky(soc-spmm), tg1[:ITEM]); acc += lat1
  gather_mega_kernel<true, false><<<CDIV(NN * 64, thr), thr, 0, stream>>>(
      a_rp, a_col, a_eid, adv, s_rp, s_col, s_eid, sdv,
      nullptr, nullptr, nullptr, nullptr,
      lat0, tg1, nullptr, lat1, acc);

  // ---- layer 1 ----
  drop_kernel<<<CDIV(nAdj, thr), thr, 0, stream>>>(adj_v, adv, nAdj, kk[3][0], kk[3][1]);
  drop_kernel<<<CDIV(nTag, thr), thr, 0, stream>>>(tag_v, tdv, nTag, kk[4][0], kk[4][1]);
  drop_kernel<<<CDIV(nSoc, thr), thr, 0, stream>>>(soc_v, sdv, nSoc, kk[5][0], kk[5][1]);

  // acc += combine(leaky(adj), leaky(soc), leaky(tag)[:ITEM]) — tag fused inline,
  // tag rows [ITEM,MM) never computed (dead past this layer).
  gather_mega_kernel<false, true><<<CDIV(NN * 64, thr), thr, 0, stream>>>(
      a_rp, a_col, a_eid, adv, s_rp, s_col, s_eid, sdv,
      t_rp, t_col, t_eid, tdv,
      lat1, nullptr, tg1 + (size_t)ITEM_N * DD, nullptr, acc);
#undef CDIV
}

// Round 4
// 992.181 us; speedup vs baseline: 2.0603x; 1.2072x over previous
//
#include <hip/hip_runtime.h>
#include <stdint.h>

// Problem constants (match reference)
#define USER_N 100000
#define ITEM_N 50000
#define TAG_N  20000
#define NN (USER_N + ITEM_N)   // 150000 interaction-graph nodes
#define MM (ITEM_N + TAG_N)    // 70000 tag-graph nodes
#define DD 64

// ---------------------------------------------------------------------------
// JAX threefry2x32 (20 rounds), bit-exact (verified: R1 absmax 0.0).
// ---------------------------------------------------------------------------
__host__ __device__ __forceinline__ void tf2x32(uint32_t k0, uint32_t k1,
                                                uint32_t x0, uint32_t x1,
                                                uint32_t* o0, uint32_t* o1) {
  uint32_t ks2 = k0 ^ k1 ^ 0x1BD11BDAu;
#define ROTL32(v, d) (((v) << (d)) | ((v) >> (32 - (d))))
#define TF_RND(d) { x0 += x1; x1 = ROTL32(x1, d); x1 ^= x0; }
  x0 += k0; x1 += k1;
  TF_RND(13) TF_RND(15) TF_RND(26) TF_RND(6)
  x0 += k1;  x1 += ks2 + 1u;
  TF_RND(17) TF_RND(29) TF_RND(16) TF_RND(24)
  x0 += ks2; x1 += k0 + 2u;
  TF_RND(13) TF_RND(15) TF_RND(26) TF_RND(6)
  x0 += k0;  x1 += k1 + 3u;
  TF_RND(17) TF_RND(29) TF_RND(16) TF_RND(24)
  x0 += k1;  x1 += ks2 + 4u;
  TF_RND(13) TF_RND(15) TF_RND(26) TF_RND(6)
  x0 += ks2; x1 += k0 + 5u;
  *o0 = x0; *o1 = x1;
#undef TF_RND
#undef ROTL32
}

// drop-edge into CSR position i: cv[i].y = vals[eid[i]] * mask(eid[i]) * (1/0.9)
// threefry counter is the ORIGINAL edge index -> bit-exact vs reference.
__global__ void drop_sorted_kernel(const float* __restrict__ vals,
                                   const int* __restrict__ eid,
                                   int2* __restrict__ cv, int n,
                                   uint32_t k0, uint32_t k1) {
  int i = blockIdx.x * blockDim.x + threadIdx.x;
  if (i >= n) return;
  int e = eid[i];
  uint32_t o0, o1;
  tf2x32(k0, k1, 0u, (uint32_t)e, &o0, &o1);
  uint32_t bits = o0 ^ o1;
  float u = __uint_as_float((bits >> 9) | 0x3F800000u) - 1.0f;
  float m = floorf(u + 0.9f);
  const float SC = (float)(1.0 / 0.9);
  cv[i].y = __float_as_int(vals[e] * m * SC);
}

// ---------------------------------------------------------------------------
// CSR build: histogram -> hierarchical exclusive scan -> scatter {col,eid}
// ---------------------------------------------------------------------------
__global__ void hist_kernel(const int* __restrict__ rows, int* __restrict__ cnt, int nE) {
  int e = blockIdx.x * blockDim.x + threadIdx.x;
  if (e < nE) atomicAdd(&cnt[rows[e]], 1);
}

__global__ void scan1_kernel(const int* __restrict__ cnt, int* __restrict__ rp,
                             int* __restrict__ bsum, int n) {
  __shared__ int s[256];
  int t = threadIdx.x;
  int base = blockIdx.x * 1024 + t * 4;
  int c0 = (base + 0 < n) ? cnt[base + 0] : 0;
  int c1 = (base + 1 < n) ? cnt[base + 1] : 0;
  int c2 = (base + 2 < n) ? cnt[base + 2] : 0;
  int c3 = (base + 3 < n) ? cnt[base + 3] : 0;
  int tsum = c0 + c1 + c2 + c3;
  s[t] = tsum;
  __syncthreads();
  for (int off = 1; off < 256; off <<= 1) {
    int v = (t >= off) ? s[t - off] : 0;
    __syncthreads();
    s[t] += v;
    __syncthreads();
  }
  int excl = s[t] - tsum;
  if (base + 0 < n) rp[base + 0] = excl;
  if (base + 1 < n) rp[base + 1] = excl + c0;
  if (base + 2 < n) rp[base + 2] = excl + c0 + c1;
  if (base + 3 < n) rp[base + 3] = excl + c0 + c1 + c2;
  if (t == 255) bsum[blockIdx.x] = s[255];
}

__global__ void scan2_kernel(int* __restrict__ bsum, int B) {
  __shared__ int s[256];
  int t = threadIdx.x;
  int v = (t < B) ? bsum[t] : 0;
  s[t] = v;
  __syncthreads();
  for (int off = 1; off < 256; off <<= 1) {
    int x = (t >= off) ? s[t - off] : 0;
    __syncthreads();
    s[t] += x;
    __syncthreads();
  }
  if (t < B) bsum[t] = s[t] - v;
}

__global__ void scan3_kernel(int* __restrict__ rp, const int* __restrict__ bsum,
                             int* __restrict__ cursor, int n, int nE) {
  int i = blockIdx.x * blockDim.x + threadIdx.x;
  if (i < n) {
    int v = rp[i] + bsum[i >> 10];
    rp[i] = v;
    cursor[i] = v;
  }
  if (i == 0) rp[n] = nE;
}

__global__ void scatter_kernel(const int* __restrict__ rows, const int* __restrict__ cols,
                               int* __restrict__ cursor,
                               int2* __restrict__ cv, int* __restrict__ eid_s, int nE) {
  int e = blockIdx.x * blockDim.x + threadIdx.x;
  if (e >= nE) return;
  int pos = atomicAdd(&cursor[rows[e]], 1);
  cv[pos].x = cols[e];
  eid_s[pos] = e;
}

// ---------------------------------------------------------------------------
// Gather SpMM core: one wave per row, lane = feature dim (scalar, as R2).
// Unroll-by-4 over edges with WAVE-UNIFORM trip counts: shfl indices j..j+3
// are < cnt for ALL lanes (cnt is wave-uniform), so every shfl source lane
// is active — this is the fix for R3's divergent-shfl bug.
// 4 independent global loads in flight per iteration; adds stay in strict
// edge order (identical summation order to the R2-verified kernel; dropped
// edges contribute v*x = +0 exactly).
// ---------------------------------------------------------------------------
__device__ __forceinline__ float gather_row(int s0, int s1,
                                            const int2* __restrict__ cv,
                                            const float* __restrict__ srcA,
                                            const float* __restrict__ srcB,
                                            int split, int lane) {
  float a = 0.0f;
  for (int base = s0; base < s1; base += 64) {
    int i = base + lane;
    int2 m = make_int2(0, 0);
    if (i < s1) m = cv[i];
    int cnt = s1 - base;
    if (cnt > 64) cnt = 64;
    int j = 0;
    for (; j + 4 <= cnt; j += 4) {
      int c0 = __shfl(m.x, j + 0);
      int c1 = __shfl(m.x, j + 1);
      int c2 = __shfl(m.x, j + 2);
      int c3 = __shfl(m.x, j + 3);
      float v0 = __uint_as_float((uint32_t)__shfl(m.y, j + 0));
      float v1 = __uint_as_float((uint32_t)__shfl(m.y, j + 1));
      float v2 = __uint_as_float((uint32_t)__shfl(m.y, j + 2));
      float v3 = __uint_as_float((uint32_t)__shfl(m.y, j + 3));
      const float* p0 = (c0 < split) ? (srcA + (size_t)c0 * DD) : (srcB + (size_t)(c0 - split) * DD);
      const float* p1 = (c1 < split) ? (srcA + (size_t)c1 * DD) : (srcB + (size_t)(c1 - split) * DD);
      const float* p2 = (c2 < split) ? (srcA + (size_t)c2 * DD) : (srcB + (size_t)(c2 - split) * DD);
      const float* p3 = (c3 < split) ? (srcA + (size_t)c3 * DD) : (srcB + (size_t)(c3 - split) * DD);
      float x0 = p0[lane];
      float x1 = p1[lane];
      float x2 = p2[lane];
      float x3 = p3[lane];
      a += v0 * x0;
      a += v1 * x1;
      a += v2 * x2;
      a += v3 * x3;
    }
    for (; j < cnt; ++j) {
      int   c = __shfl(m.x, j);
      float v = __uint_as_float((uint32_t)__shfl(m.y, j));
      const float* p = (c < split) ? (srcA + (size_t)c * DD) : (srcB + (size_t)(c - split) * DD);
      a += v * p[lane];
    }
  }
  return a;
}

__device__ __forceinline__ float lky(float x) { return x >= 0.0f ? x : 0.5f * x; }

// Tag-node rows only (rr in [0,TAG_N), graph row = ITEM_N+rr): out = leaky(spmm).
// Needed as next-layer tag sources; item rows of the tag graph are fused into mega.
__global__ void gather_tagrows_kernel(const int* __restrict__ rp, const int2* __restrict__ cv,
                                      const float* __restrict__ srcA, const float* __restrict__ srcB,
                                      float* __restrict__ out) {
  int rr = (blockIdx.x * blockDim.x + threadIdx.x) >> 6;
  if (rr >= TAG_N) return;
  int lane = threadIdx.x & 63;
  int r = rr + ITEM_N;
  float a = gather_row(rp[r], rp[r + 1], cv, srcA, srcB, ITEM_N, lane);
  out[(size_t)rr * DD + lane] = lky(a);
}

// Mega gather over NN rows; tag gather for item rows fused inline.
// o = leaky(adj) + (r<USER ? leaky(soc) : leaky(tag_row)); acc += o; [latOut = o]
template <bool STORE>
__global__ void gather_mega_kernel(
    const int* __restrict__ arp, const int2* __restrict__ acv,
    const int* __restrict__ srp, const int2* __restrict__ scv,
    const int* __restrict__ trp, const int2* __restrict__ tcv,
    const float* __restrict__ lat,    // NN x 64: src for adj & soc (& tag item part)
    const float* __restrict__ tagB,   // tag-node src rows (tEmbeds or tg1)
    float* __restrict__ latOut, float* __restrict__ acc) {
  int r = (blockIdx.x * blockDim.x + threadIdx.x) >> 6;
  if (r >= NN) return;
  int lane = threadIdx.x & 63;
  float t = lky(gather_row(arp[r], arp[r + 1], acv, lat, lat, NN, lane));
  float b;
  if (r < USER_N) {
    b = lky(gather_row(srp[r], srp[r + 1], scv, lat, lat, NN, lane));
  } else {
    int tr = r - USER_N;
    b = lky(gather_row(trp[tr], trp[tr + 1], tcv,
                       lat + (size_t)USER_N * DD, tagB, ITEM_N, lane));
  }
  float o = t + b;
  size_t idx = (size_t)r * DD + lane;
  acc[idx] += o;
  if (STORE) latOut[idx] = o;
}

// acc = lat0 = concat(uEmbeds, iEmbeds); separate lat0 copy (acc is RMW'd later).
__global__ void init_kernel(const float4* __restrict__ u, const float4* __restrict__ it,
                            float4* __restrict__ lat0, float4* __restrict__ acc) {
  int idx = blockIdx.x * blockDim.x + threadIdx.x;  // over NN*16 float4s
  if (idx >= NN * 16) return;
  const int uN = USER_N * 16;
  float4 v = (idx < uN) ? u[idx] : it[idx - uN];
  lat0[idx] = v;
  acc[idx] = v;
}

extern "C" void kernel_launch(void* const* d_in, const int* in_sizes, int n_in,
                              void* d_out, int out_size, void* d_ws, size_t ws_size,
                              hipStream_t stream) {
  const float* uE    = (const float*)d_in[0];
  const float* iE    = (const float*)d_in[1];
  const float* tEm   = (const float*)d_in[2];
  const int*   adj_r = (const int*)d_in[3];
  const int*   adj_c = (const int*)d_in[4];
  const float* adj_v = (const float*)d_in[5];
  const int*   tag_r = (const int*)d_in[6];
  const int*   tag_c = (const int*)d_in[7];
  const float* tag_v = (const float*)d_in[8];
  const int*   soc_r = (const int*)d_in[9];
  const int*   soc_c = (const int*)d_in[10];
  const float* soc_v = (const float*)d_in[11];
  const int nAdj = in_sizes[5], nTag = in_sizes[8], nSoc = in_sizes[11];

  float* acc = (float*)d_out;

  // Workspace layout (~132 MB; R1's 146.5 MB fit fine)
  float* lat0 = (float*)d_ws;                      // NN*DD
  float* lat1 = lat0 + (size_t)NN * DD;            // NN*DD
  float* tg1  = lat1 + (size_t)NN * DD;            // TAG_N*DD (tag-node rows only)
  int2* a_cv = (int2*)(tg1 + (size_t)TAG_N * DD);  // nAdj  {col, val}
  int2* t_cv = a_cv + nAdj;                        // nTag
  int2* s_cv = t_cv + nTag;                        // nSoc
  int* ip    = (int*)(s_cv + nSoc);
  int* a_eid = ip;  ip += nAdj;
  int* t_eid = ip;  ip += nTag;
  int* s_eid = ip;  ip += nSoc;
  int* a_rp  = ip;  ip += NN + 1;
  int* a_cur = ip;  ip += NN;
  int* t_rp  = ip;  ip += MM + 1;
  int* t_cur = ip;  ip += MM;
  int* s_rp  = ip;  ip += USER_N + 1;
  int* s_cur = ip;  ip += USER_N;
  int* bsum  = ip;  ip += 256;

  // fold_in(key(42), j) for j=0..5 (host-side, deterministic)
  uint32_t kk[6][2];
  for (uint32_t j = 0; j < 6; ++j) tf2x32(0u, 42u, 0u, j, &kk[j][0], &kk[j][1]);

  const int thr = 256;
#define CDIV(a, b) (((a) + (b) - 1) / (b))

  // ---- CSR build (once per call; reused across both layers) ----
  struct G { const int* rows; const int* cols; int n; int nE; int* rp; int* cur; int2* cv; int* eid; };
  G gs[3] = {
      {adj_r, adj_c, NN,     nAdj, a_rp, a_cur, a_cv, a_eid},
      {tag_r, tag_c, MM,     nTag, t_rp, t_cur, t_cv, t_eid},
      {soc_r, soc_c, USER_N, nSoc, s_rp, s_cur, s_cv, s_eid},
  };
  for (int g = 0; g < 3; ++g) {
    hipMemsetAsync(gs[g].cur, 0, (size_t)gs[g].n * sizeof(int), stream);
    hist_kernel<<<CDIV(gs[g].nE, thr), thr, 0, stream>>>(gs[g].rows, gs[g].cur, gs[g].nE);
    int B = CDIV(gs[g].n, 1024);
    scan1_kernel<<<B, 256, 0, stream>>>(gs[g].cur, gs[g].rp, bsum, gs[g].n);
    scan2_kernel<<<1, 256, 0, stream>>>(bsum, B);
    scan3_kernel<<<CDIV(gs[g].n, thr), thr, 0, stream>>>(gs[g].rp, bsum, gs[g].cur, gs[g].n, gs[g].nE);
    scatter_kernel<<<CDIV(gs[g].nE, thr), thr, 0, stream>>>(gs[g].rows, gs[g].cols, gs[g].cur,
                                                            gs[g].cv, gs[g].eid, gs[g].nE);
  }

  // ---- init: acc = lat0 = concat(u, i) ----
  init_kernel<<<CDIV(NN * 16, thr), thr, 0, stream>>>(
      (const float4*)uE, (const float4*)iE, (float4*)lat0, (float4*)acc);

  // ---- layer 0 ----
  drop_sorted_kernel<<<CDIV(nAdj, thr), thr, 0, stream>>>(adj_v, a_eid, a_cv, nAdj, kk[0][0], kk[0][1]);
  drop_sorted_kernel<<<CDIV(nTag, thr), thr, 0, stream>>>(tag_v, t_eid, t_cv, nTag, kk[1][0], kk[1][1]);
  drop_sorted_kernel<<<CDIV(nSoc, thr), thr, 0, stream>>>(soc_v, s_eid, s_cv, nSoc, kk[2][0], kk[2][1]);

  // tg1 = leaky(tag-spmm) for tag-node rows (needed as layer-1 tag sources)
  gather_tagrows_kernel<<<CDIV(TAG_N * 64, thr), thr, 0, stream>>>(
      t_rp, t_cv, lat0 + (size_t)USER_N * DD, tEm, tg1);

  // lat1 = combine(leaky(adj), leaky(soc) | leaky(tag item rows)); acc += lat1
  gather_mega_kernel<true><<<CDIV(NN * 64, thr), thr, 0, stream>>>(
      a_rp, a_cv, s_rp, s_cv, t_rp, t_cv, lat0, tEm, lat1, acc);

  // ---- layer 1 ----
  drop_sorted_kernel<<<CDIV(nAdj, thr), thr, 0, stream>>>(adj_v, a_eid, a_cv, nAdj, kk[3][0], kk[3][1]);
  drop_sorted_kernel<<<CDIV(nTag, thr), thr, 0, stream>>>(tag_v, t_eid, t_cv, nTag, kk[4][0], kk[4][1]);
  drop_sorted_kernel<<<CDIV(nSoc, thr), thr, 0, stream>>>(soc_v, s_eid, s_cv, nSoc, kk[5][0], kk[5][1]);

  // acc += combine(leaky(adj), leaky(soc) | leaky(tag item rows)), tag srcs = tg1
  gather_mega_kernel<false><<<CDIV(NN * 64, thr), thr, 0, stream>>>(
      a_rp, a_cv, s_rp, s_cv, t_rp, t_cv, lat1, tg1, nullptr, acc);
#undef CDIV
}

// Round 5
// 849.603 us; speedup vs baseline: 2.4060x; 1.1678x over previous
//
#include <hip/hip_runtime.h>
#include <stdint.h>

// Problem constants (match reference)
#define USER_N 100000
#define ITEM_N 50000
#define TAG_N  20000
#define NN (USER_N + ITEM_N)   // 150000 interaction-graph nodes
#define MM (ITEM_N + TAG_N)    // 70000 tag-graph nodes
#define DD 64

// ---------------------------------------------------------------------------
// JAX threefry2x32 (20 rounds), bit-exact (verified: R1 absmax 0.0).
// ---------------------------------------------------------------------------
__host__ __device__ __forceinline__ void tf2x32(uint32_t k0, uint32_t k1,
                                                uint32_t x0, uint32_t x1,
                                                uint32_t* o0, uint32_t* o1) {
  uint32_t ks2 = k0 ^ k1 ^ 0x1BD11BDAu;
#define ROTL32(v, d) (((v) << (d)) | ((v) >> (32 - (d))))
#define TF_RND(d) { x0 += x1; x1 = ROTL32(x1, d); x1 ^= x0; }
  x0 += k0; x1 += k1;
  TF_RND(13) TF_RND(15) TF_RND(26) TF_RND(6)
  x0 += k1;  x1 += ks2 + 1u;
  TF_RND(17) TF_RND(29) TF_RND(16) TF_RND(24)
  x0 += ks2; x1 += k0 + 2u;
  TF_RND(13) TF_RND(15) TF_RND(26) TF_RND(6)
  x0 += k0;  x1 += k1 + 3u;
  TF_RND(17) TF_RND(29) TF_RND(16) TF_RND(24)
  x0 += k1;  x1 += ks2 + 4u;
  TF_RND(13) TF_RND(15) TF_RND(26) TF_RND(6)
  x0 += ks2; x1 += k0 + 5u;
  *o0 = x0; *o1 = x1;
#undef TF_RND
#undef ROTL32
}

// mask(e; key) * (1/0.9) factor, bit-exact vs jax uniform+floor
__device__ __forceinline__ float drop_mask(uint32_t e, uint32_t k0, uint32_t k1) {
  uint32_t o0, o1;
  tf2x32(k0, k1, 0u, e, &o0, &o1);
  uint32_t bits = o0 ^ o1;
  float u = __uint_as_float((bits >> 9) | 0x3F800000u) - 1.0f;
  return floorf(u + 0.9f);
}

// ---------------------------------------------------------------------------
// CSR build: histogram -> hierarchical exclusive scan -> fused scatter.
// Scatter writes ONE 16B record per edge {col, val_l0, val_l1, 0}: 1 dirty
// line per edge (vs 2 in the col+eid scheme) and no separate drop kernels.
// ---------------------------------------------------------------------------
__global__ void hist_kernel(const int* __restrict__ rows, int* __restrict__ cnt, int nE) {
  int e = blockIdx.x * blockDim.x + threadIdx.x;
  if (e < nE) atomicAdd(&cnt[rows[e]], 1);
}

__global__ void scan1_kernel(const int* __restrict__ cnt, int* __restrict__ rp,
                             int* __restrict__ bsum, int n) {
  __shared__ int s[256];
  int t = threadIdx.x;
  int base = blockIdx.x * 1024 + t * 4;
  int c0 = (base + 0 < n) ? cnt[base + 0] : 0;
  int c1 = (base + 1 < n) ? cnt[base + 1] : 0;
  int c2 = (base + 2 < n) ? cnt[base + 2] : 0;
  int c3 = (base + 3 < n) ? cnt[base + 3] : 0;
  int tsum = c0 + c1 + c2 + c3;
  s[t] = tsum;
  __syncthreads();
  for (int off = 1; off < 256; off <<= 1) {
    int v = (t >= off) ? s[t - off] : 0;
    __syncthreads();
    s[t] += v;
    __syncthreads();
  }
  int excl = s[t] - tsum;
  if (base + 0 < n) rp[base + 0] = excl;
  if (base + 1 < n) rp[base + 1] = excl + c0;
  if (base + 2 < n) rp[base + 2] = excl + c0 + c1;
  if (base + 3 < n) rp[base + 3] = excl + c0 + c1 + c2;
  if (t == 255) bsum[blockIdx.x] = s[255];
}

__global__ void scan2_kernel(int* __restrict__ bsum, int B) {
  __shared__ int s[256];
  int t = threadIdx.x;
  int v = (t < B) ? bsum[t] : 0;
  s[t] = v;
  __syncthreads();
  for (int off = 1; off < 256; off <<= 1) {
    int x = (t >= off) ? s[t - off] : 0;
    __syncthreads();
    s[t] += x;
    __syncthreads();
  }
  if (t < B) bsum[t] = s[t] - v;
}

__global__ void scan3_kernel(int* __restrict__ rp, const int* __restrict__ bsum,
                             int* __restrict__ cursor, int n, int nE) {
  int i = blockIdx.x * blockDim.x + threadIdx.x;
  if (i < n) {
    int v = rp[i] + bsum[i >> 10];
    rp[i] = v;
    cursor[i] = v;
  }
  if (i == 0) rp[n] = nE;
}

// Fused scatter: per original edge e, compute BOTH layers' dropped values
// (threefry keyed on e -> bit-exact regardless of CSR position) and store one
// aligned int4 record at the atomically-claimed CSR slot.
__global__ void scatter_fused_kernel(const int* __restrict__ rows, const int* __restrict__ cols,
                                     const float* __restrict__ vals,
                                     int* __restrict__ cursor, int4* __restrict__ rec, int nE,
                                     uint32_t ka0, uint32_t ka1, uint32_t kb0, uint32_t kb1) {
  int e = blockIdx.x * blockDim.x + threadIdx.x;
  if (e >= nE) return;
  const float SC = (float)(1.0 / 0.9);
  float v  = vals[e];
  float v0 = v * drop_mask((uint32_t)e, ka0, ka1) * SC;
  float v1 = v * drop_mask((uint32_t)e, kb0, kb1) * SC;
  int pos = atomicAdd(&cursor[rows[e]], 1);
  rec[pos] = make_int4(cols[e], __float_as_int(v0), __float_as_int(v1), 0);
}

// ---------------------------------------------------------------------------
// Gather SpMM core: one wave per row, lane = feature dim. Wave-uniform
// unroll-by-4 (R4-verified: all shfl source lanes active), 4 independent row
// loads in flight, adds in strict edge order. VS picks the layer's value slot.
// ---------------------------------------------------------------------------
template <int VS>
__device__ __forceinline__ float gather_row(int s0, int s1,
                                            const int4* __restrict__ rec,
                                            const float* __restrict__ srcA,
                                            const float* __restrict__ srcB,
                                            int split, int lane) {
  float a = 0.0f;
  for (int base = s0; base < s1; base += 64) {
    int i = base + lane;
    int4 m = make_int4(0, 0, 0, 0);
    if (i < s1) m = rec[i];
    int mv = VS ? m.z : m.y;
    int cnt = s1 - base;
    if (cnt > 64) cnt = 64;
    int j = 0;
    for (; j + 4 <= cnt; j += 4) {
      int c0 = __shfl(m.x, j + 0);
      int c1 = __shfl(m.x, j + 1);
      int c2 = __shfl(m.x, j + 2);
      int c3 = __shfl(m.x, j + 3);
      float v0 = __uint_as_float((uint32_t)__shfl(mv, j + 0));
      float v1 = __uint_as_float((uint32_t)__shfl(mv, j + 1));
      float v2 = __uint_as_float((uint32_t)__shfl(mv, j + 2));
      float v3 = __uint_as_float((uint32_t)__shfl(mv, j + 3));
      const float* p0 = (c0 < split) ? (srcA + (size_t)c0 * DD) : (srcB + (size_t)(c0 - split) * DD);
      const float* p1 = (c1 < split) ? (srcA + (size_t)c1 * DD) : (srcB + (size_t)(c1 - split) * DD);
      const float* p2 = (c2 < split) ? (srcA + (size_t)c2 * DD) : (srcB + (size_t)(c2 - split) * DD);
      const float* p3 = (c3 < split) ? (srcA + (size_t)c3 * DD) : (srcB + (size_t)(c3 - split) * DD);
      float x0 = p0[lane];
      float x1 = p1[lane];
      float x2 = p2[lane];
      float x3 = p3[lane];
      a += v0 * x0;
      a += v1 * x1;
      a += v2 * x2;
      a += v3 * x3;
    }
    for (; j < cnt; ++j) {
      int   c = __shfl(m.x, j);
      float v = __uint_as_float((uint32_t)__shfl(mv, j));
      const float* p = (c < split) ? (srcA + (size_t)c * DD) : (srcB + (size_t)(c - split) * DD);
      a += v * p[lane];
    }
  }
  return a;
}

__device__ __forceinline__ float lky(float x) { return x >= 0.0f ? x : 0.5f * x; }

// Tag-node rows only (rr in [0,TAG_N), graph row = ITEM_N+rr): out = leaky(spmm).
// Layer-0 values (VS=0); result is the layer-1 tag source.
__global__ void gather_tagrows_kernel(const int* __restrict__ rp, const int4* __restrict__ rec,
                                      const float* __restrict__ srcA, const float* __restrict__ srcB,
                                      float* __restrict__ out) {
  int rr = (blockIdx.x * blockDim.x + threadIdx.x) >> 6;
  if (rr >= TAG_N) return;
  int lane = threadIdx.x & 63;
  int r = rr + ITEM_N;
  float a = gather_row<0>(rp[r], rp[r + 1], rec, srcA, srcB, ITEM_N, lane);
  out[(size_t)rr * DD + lane] = lky(a);
}

// Mega gather over NN rows; tag gather for item rows fused inline.
// o = leaky(adj) + (r<USER ? leaky(soc) : leaky(tag_row))
// FINAL=false (layer 0): latOut = o            (no acc RMW)
// FINAL=true  (layer 1): acc += lat[row] + o   (lat == lat1, folds layer-0 acc add)
template <int VS, bool FINAL>
__global__ void gather_mega_kernel(
    const int* __restrict__ arp, const int4* __restrict__ arec,
    const int* __restrict__ srp, const int4* __restrict__ srec,
    const int* __restrict__ trp, const int4* __restrict__ trec,
    const float* __restrict__ lat,    // NN x 64: src for adj & soc (& tag item part)
    const float* __restrict__ tagB,   // tag-node src rows (tEmbeds or tg1)
    float* __restrict__ latOut, float* __restrict__ acc) {
  int r = (blockIdx.x * blockDim.x + threadIdx.x) >> 6;
  if (r >= NN) return;
  int lane = threadIdx.x & 63;
  float t = lky(gather_row<VS>(arp[r], arp[r + 1], arec, lat, lat, NN, lane));
  float b;
  if (r < USER_N) {
    b = lky(gather_row<VS>(srp[r], srp[r + 1], srec, lat, lat, NN, lane));
  } else {
    int tr = r - USER_N;
    b = lky(gather_row<VS>(trp[tr], trp[tr + 1], trec,
                           lat + (size_t)USER_N * DD, tagB, ITEM_N, lane));
  }
  float o = t + b;
  size_t idx = (size_t)r * DD + lane;
  if (FINAL) {
    acc[idx] += lat[idx] + o;
  } else {
    latOut[idx] = o;
  }
}

// acc = lat0 = concat(uEmbeds, iEmbeds). acc doubles as the layer-0 gather
// source (layer 0 writes only lat1, so no aliasing hazard).
__global__ void init_kernel(const float4* __restrict__ u, const float4* __restrict__ it,
                            float4* __restrict__ acc) {
  int idx = blockIdx.x * blockDim.x + threadIdx.x;  // over NN*16 float4s
  if (idx >= NN * 16) return;
  const int uN = USER_N * 16;
  acc[idx] = (idx < uN) ? u[idx] : it[idx - uN];
}

extern "C" void kernel_launch(void* const* d_in, const int* in_sizes, int n_in,
                              void* d_out, int out_size, void* d_ws, size_t ws_size,
                              hipStream_t stream) {
  const float* uE    = (const float*)d_in[0];
  const float* iE    = (const float*)d_in[1];
  const float* tEm   = (const float*)d_in[2];
  const int*   adj_r = (const int*)d_in[3];
  const int*   adj_c = (const int*)d_in[4];
  const float* adj_v = (const float*)d_in[5];
  const int*   tag_r = (const int*)d_in[6];
  const int*   tag_c = (const int*)d_in[7];
  const float* tag_v = (const float*)d_in[8];
  const int*   soc_r = (const int*)d_in[9];
  const int*   soc_c = (const int*)d_in[10];
  const float* soc_v = (const float*)d_in[11];
  const int nAdj = in_sizes[5], nTag = in_sizes[8], nSoc = in_sizes[11];

  float* acc = (float*)d_out;

  // Workspace layout (~110 MB; R1's 146.5 MB fit fine)
  int4* a_rec = (int4*)d_ws;                       // nAdj  {col, v_l0, v_l1, 0}
  int4* t_rec = a_rec + nAdj;                      // nTag
  int4* s_rec = t_rec + nTag;                      // nSoc
  float* lat1 = (float*)(s_rec + nSoc);            // NN*DD
  float* tg1  = lat1 + (size_t)NN * DD;            // TAG_N*DD (tag-node rows only)
  int* ip    = (int*)(tg1 + (size_t)TAG_N * DD);
  int* a_rp  = ip;  ip += NN + 1;
  int* a_cur = ip;  ip += NN;
  int* t_rp  = ip;  ip += MM + 1;
  int* t_cur = ip;  ip += MM;
  int* s_rp  = ip;  ip += USER_N + 1;
  int* s_cur = ip;  ip += USER_N;
  int* bsum  = ip;  ip += 256;

  // fold_in(key(42), j) for j=0..5 (host-side, deterministic)
  uint32_t kk[6][2];
  for (uint32_t j = 0; j < 6; ++j) tf2x32(0u, 42u, 0u, j, &kk[j][0], &kk[j][1]);

  const int thr = 256;
#define CDIV(a, b) (((a) + (b) - 1) / (b))

  // ---- CSR build (once per call; records carry both layers' values) ----
  struct G { const int* rows; const int* cols; const float* vals; int n; int nE;
             int* rp; int* cur; int4* rec; int k0; int k1; };
  G gs[3] = {
      {adj_r, adj_c, adj_v, NN,     nAdj, a_rp, a_cur, a_rec, 0, 3},
      {tag_r, tag_c, tag_v, MM,     nTag, t_rp, t_cur, t_rec, 1, 4},
      {soc_r, soc_c, soc_v, USER_N, nSoc, s_rp, s_cur, s_rec, 2, 5},
  };
  for (int g = 0; g < 3; ++g) {
    hipMemsetAsync(gs[g].cur, 0, (size_t)gs[g].n * sizeof(int), stream);
    hist_kernel<<<CDIV(gs[g].nE, thr), thr, 0, stream>>>(gs[g].rows, gs[g].cur, gs[g].nE);
    int B = CDIV(gs[g].n, 1024);
    scan1_kernel<<<B, 256, 0, stream>>>(gs[g].cur, gs[g].rp, bsum, gs[g].n);
    scan2_kernel<<<1, 256, 0, stream>>>(bsum, B);
    scan3_kernel<<<CDIV(gs[g].n, thr), thr, 0, stream>>>(gs[g].rp, bsum, gs[g].cur, gs[g].n, gs[g].nE);
    scatter_fused_kernel<<<CDIV(gs[g].nE, thr), thr, 0, stream>>>(
        gs[g].rows, gs[g].cols, gs[g].vals, gs[g].cur, gs[g].rec, gs[g].nE,
        kk[gs[g].k0][0], kk[gs[g].k0][1], kk[gs[g].k1][0], kk[gs[g].k1][1]);
  }

  // ---- init: acc = lat0 = concat(u, i) ----
  init_kernel<<<CDIV(NN * 16, thr), thr, 0, stream>>>(
      (const float4*)uE, (const float4*)iE, (float4*)acc);

  // ---- layer 0 ----
  // tg1 = leaky(tag-spmm) for tag-node rows (layer-1 tag sources)
  gather_tagrows_kernel<<<CDIV(TAG_N * 64, thr), thr, 0, stream>>>(
      t_rp, t_rec, acc + (size_t)USER_N * DD, tEm, tg1);

  // lat1 = combine(leaky(adj), leaky(soc) | leaky(tag item rows)); acc untouched
  gather_mega_kernel<0, false><<<CDIV(NN * 64, thr), thr, 0, stream>>>(
      a_rp, a_rec, s_rp, s_rec, t_rp, t_rec, acc, tEm, lat1, nullptr);

  // ---- layer 1 ----
  // acc += lat1 + combine(leaky(adj), leaky(soc) | leaky(tag item rows))
  gather_mega_kernel<1, true><<<CDIV(NN * 64, thr), thr, 0, stream>>>(
      a_rp, a_rec, s_rp, s_rec, t_rp, t_rec, lat1, tg1, nullptr, acc);
#undef CDIV
}